// Round 17
// baseline (55.722 us; speedup 1.0000x reference)
//
#include <hip/hip_runtime.h>

#define NN 128
#define CCH 16
#define BB 4
#define HID 128
#define DOUT 128

typedef float v2f __attribute__((ext_vector_type(2)));

// ---------------------------------------------------------------------------
// Single fused kernel, split-k. Block = (b, row p), 1024 threads = 16 waves,
// (1024,8) -> 2 blocks/CU, 8192 waves = full machine. XCD swizzle kept.
//
// Phase 1: thread (kh = t>>9, c = (t>>5)&15, qg = t&31) owns channel c,
//   FOUR q's (q0 = qg*4), and HALF the hidden units (k = kh*64 .. +63).
//   Same proven v2f body as R16; per-thread k-chain halved (convoy theory).
//   Partials land in two disjoint LDS planes (no race).
// Diag: masked partial, width-32 shuffle (32 lanes share (c,kh)), combine.
// Phase 2: out[c][m] = plane0 + plane1 (+bb1 folded into plane0's writes);
//   wave wv -> 8 d's (wave-uniform -> scalar Wc/bc), lane = m-pair.
// ---------------------------------------------------------------------------
__global__ __launch_bounds__(1024, 8) void fused_rey(
    const float* __restrict__ x,
    const float* __restrict__ W1, const float* __restrict__ b1,
    const float* __restrict__ W2, const float* __restrict__ b2,
    const float* __restrict__ Wc, const float* __restrict__ bc,
    float* __restrict__ y)
{
    __shared__ float s_h[2][CCH][NN];   // 16 KB: per-k-half h1 partial planes
    __shared__ float s_dg[2][CCH];      // per-k-half diag partials

    const int t    = threadIdx.x;
    const int bid0 = blockIdx.x;
    const int bid  = ((bid0 & 7) << 6) | (bid0 >> 3);   // XCD-contiguous (bijective)
    const int p    = bid & 127;
    const int b    = bid >> 7;
    const int kh   = t >> 9;            // 0..1 (wave-uniform)
    const int c    = (t >> 5) & 15;     // 0..15 (half-wave uniform)
    const int qg   = t & 31;
    const int q0   = qg * 4;            // q quad {q0..q0+3}

    const float* xm = x + (((size_t)(b * CCH + c)) << 14);

    // per-thread x loads (strided ones served by per-XCD L2 post-swizzle)
    const float4 vpq = *reinterpret_cast<const float4*>(&xm[p * NN + q0]);  // coalesced
    const v2f xpq01 = { vpq.x, vpq.y }, xpq23 = { vpq.z, vpq.w };
    const v2f xqp01 = { xm[q0 * NN + p],       xm[(q0 + 1) * NN + p] };
    const v2f xqp23 = { xm[(q0 + 2) * NN + p], xm[(q0 + 3) * NN + p] };
    const v2f xqq01 = { xm[q0 * (NN + 1)],       xm[(q0 + 1) * (NN + 1)] };
    const v2f xqq23 = { xm[(q0 + 2) * (NN + 1)], xm[(q0 + 3) * (NN + 1)] };
    const float xpp = xm[p * (NN + 1)];

    const float bb0 = b2[0], bb1 = b2[1];
    const v2f z2 = { 0.f, 0.f };
    v2f h0a = z2, h0b = z2, h1a = z2, h1b = z2;

    // wave-uniform weight pointers for this k-half
    const float4* w1p = reinterpret_cast<const float4*>(W1) + kh * 64;
    const float* b1p  = b1 + kh * 64;
    const float* w20p = W2 + kh * 64;
    const float* w21p = W2 + HID + kh * 64;

    // ---- phase 1: 64-k hidden loop (v2f body, 4 cells/thread/k) ----
    #pragma unroll 4
    for (int j = 0; j < 64; ++j) {
        const float4 w  = w1p[j];          // s_load_dwordx4
        const float b1k = b1p[j];
        const float w20 = w20p[j];
        const float w21 = w21p[j];
        const float a = fmaf(w.x, xpp, b1k);       // q-invariant
        const v2f av  = { a, a };
        const v2f wy  = { w.y, w.y }, wz = { w.z, w.z }, ww = { w.w, w.w };
        const v2f w20v = { w20, w20 }, w21v = { w21, w21 };

        v2f hd0 = __builtin_elementwise_fma(wy, xpq01, av);
        hd0 = __builtin_elementwise_fma(wz, xqp01, hd0);
        hd0 = __builtin_elementwise_fma(ww, xqq01, hd0);
        hd0 = __builtin_elementwise_max(hd0, z2);
        h0a = __builtin_elementwise_fma(w20v, hd0, h0a);
        h1a = __builtin_elementwise_fma(w21v, hd0, h1a);

        v2f hd1 = __builtin_elementwise_fma(wy, xpq23, av);
        hd1 = __builtin_elementwise_fma(wz, xqp23, hd1);
        hd1 = __builtin_elementwise_fma(ww, xqq23, hd1);
        hd1 = __builtin_elementwise_max(hd1, z2);
        h0b = __builtin_elementwise_fma(w20v, hd1, h0b);
        h1b = __builtin_elementwise_fma(w21v, hd1, h1b);
    }

    // h1 partial -> own LDS plane (bb1 folded into plane 0 only)
    const float bias = (kh == 0) ? bb1 : 0.f;
    float4 o;
    o.x = h1a[0] + bias; o.y = h1a[1] + bias;
    o.z = h1b[0] + bias; o.w = h1b[1] + bias;
    *reinterpret_cast<float4*>(&s_h[kh][c][q0]) = o;

    // diag partial: mask q==p, reduce across the 32 lanes sharing (c,kh)
    float s = ((q0 == p)     ? 0.f : h0a[0]) + ((q0 + 1 == p) ? 0.f : h0a[1])
            + ((q0 + 2 == p) ? 0.f : h0b[0]) + ((q0 + 3 == p) ? 0.f : h0b[1]);
    #pragma unroll
    for (int off = 16; off > 0; off >>= 1)
        s += __shfl_down(s, off, 32);
    if (qg == 0) s_dg[kh][c] = s;

    __syncthreads();
    if (t < CCH) {
        s_h[0][t][p] = (s_dg[0][t] + s_dg[1][t]) * (1.0f / (NN - 1)) + bb0;
        s_h[1][t][p] = 0.f;
    }
    __syncthreads();

    // ---- phase 2: y[b,d,p,:] = relu(sum_c (plane0+plane1)*Wc[d][c] + bc[d]) --
    const int wv   = t >> 6;           // 0..15 -> 8 d's each (wave-uniform)
    const int lane = t & 63;
    const int m0   = lane * 2;
    v2f r[CCH];
    #pragma unroll
    for (int cc = 0; cc < CCH; ++cc)
        r[cc] = *reinterpret_cast<const v2f*>(&s_h[0][cc][m0])
              + *reinterpret_cast<const v2f*>(&s_h[1][cc][m0]);

    #pragma unroll 2
    for (int dd = 0; dd < 8; ++dd) {
        const int d = wv * 8 + dd;         // wave-uniform
        const float bcv = bc[d];           // scalar load
        v2f acc = { bcv, bcv };
        #pragma unroll
        for (int cc = 0; cc < CCH; ++cc) {
            const float wcf = Wc[d * CCH + cc];   // scalar load
            acc = __builtin_elementwise_fma((v2f){ wcf, wcf }, r[cc], acc);
        }
        acc = __builtin_elementwise_max(acc, z2);
        *reinterpret_cast<v2f*>(
            &y[(((size_t)(b * DOUT + d)) * NN + p) * NN + m0]) = acc;
    }
}

extern "C" void kernel_launch(void* const* d_in, const int* in_sizes, int n_in,
                              void* d_out, int out_size, void* d_ws, size_t ws_size,
                              hipStream_t stream) {
    const float* x  = (const float*)d_in[0];
    const float* W1 = (const float*)d_in[1];
    const float* b1 = (const float*)d_in[2];
    const float* W2 = (const float*)d_in[3];
    const float* b2 = (const float*)d_in[4];
    const float* Wc = (const float*)d_in[5];
    const float* bc = (const float*)d_in[6];
    float* y = (float*)d_out;

    fused_rey<<<dim3(BB * NN), 1024, 0, stream>>>(x, W1, b1, W2, b2, Wc, bc, y);
}